// Round 10
// baseline (559.299 us; speedup 1.0000x reference)
//
#include <hip/hip_runtime.h>
#include <hip/hip_bf16.h>

#define N_USERS 100000
#define N_ITEMS 150000
#define N_NODES 250000
#define N_EDGES 4000000
#define DIM     64
#define N_ELEM  (N_NODES * DIM)      // 16,000,000
#define U_ELEM  (N_USERS * DIM)      //  6,400,000
#define BSHIFT  10
#define BNODES  (1 << BSHIFT)        // 1024 nodes per bucket
#define NBUCKET ((N_NODES + BNODES - 1) >> BSHIFT)   // 245
#define CHUNK   4096
#define NB_HIST ((N_EDGES + CHUNK - 1) / CHUNK)      // 977

typedef _Float16 h2 __attribute__((ext_vector_type(2)));
typedef unsigned int u32x4 __attribute__((ext_vector_type(4)));
typedef float f32x4 __attribute__((ext_vector_type(4)));

// ---------------- bf16 helpers (bit-level, RNE pack) ----------------
__device__ __forceinline__ float bflo(unsigned int u) { return __uint_as_float(u << 16); }
__device__ __forceinline__ float bfhi(unsigned int u) { return __uint_as_float(u & 0xffff0000u); }
__device__ __forceinline__ unsigned int bfr(float f) {   // f32 -> bf16 bits, round-nearest-even
    unsigned int u = __float_as_uint(f);
    return (u + 0x7fffu + ((u >> 16) & 1u)) >> 16;
}
__device__ __forceinline__ unsigned int pk(float a, float b) {  // two bf16 packed, a in low half
    return bfr(a) | (bfr(b) << 16);
}
// ---------------- f16 helpers (half2-in-uint) ----------------
__device__ __forceinline__ h2 uh(unsigned int u) {
    union { unsigned int u; h2 h; } c; c.u = u; return c.h;
}
__device__ __forceinline__ unsigned int pkh(float a, float b) {  // two f16 packed
    union { h2 h; unsigned int u; } c;
    c.h.x = (_Float16)a; c.h.y = (_Float16)b;
    return c.u;
}
// ---------------- nontemporal access helpers ----------------
__device__ __forceinline__ int2 ldnt2(const int2* p) {
    unsigned long long u = __builtin_nontemporal_load((const unsigned long long*)p);
    int2 r; r.x = (int)u; r.y = (int)(u >> 32); return r;
}
__device__ __forceinline__ uint4 ldnt4(const void* p) {
    u32x4 v = __builtin_nontemporal_load((const u32x4*)p);
    uint4 r; r.x = v.x; r.y = v.y; r.z = v.z; r.w = v.w; return r;
}
__device__ __forceinline__ void stnt4(void* p, uint4 v) {
    u32x4 t; t.x = v.x; t.y = v.y; t.z = v.z; t.w = v.w;
    __builtin_nontemporal_store(t, (u32x4*)p);
}
__device__ __forceinline__ void stnt4f(void* p, float4 v) {
    f32x4 t; t.x = v.x; t.y = v.y; t.z = v.z; t.w = v.w;
    __builtin_nontemporal_store(t, (f32x4*)p);
}
__device__ __forceinline__ float4 ldnt4f(const void* p) {
    f32x4 v = __builtin_nontemporal_load((const f32x4*)p);
    float4 r; r.x = v.x; r.y = v.y; r.z = v.z; r.w = v.w; return r;
}

// ---- stage 1: per-chunk bucket histogram (int4 reads) + probe fused into block 0 ----
__global__ void hist_bucket(const int* __restrict__ dst, const unsigned short* __restrict__ ue,
                            int* __restrict__ flag, int* __restrict__ M,
                            int* __restrict__ tot) {
    __shared__ int h[NBUCKET];
    for (int b = threadIdx.x; b < NBUCKET; b += blockDim.x) h[b] = 0;
    if (blockIdx.x == 0 && threadIdx.x < 64) {   // dtype probe (wave 0 of block 0)
        int lane = threadIdx.x;
        int bad = 0;
        #pragma unroll
        for (int k = 0; k < 8; ++k) {
            unsigned int b = ((unsigned int)ue[lane * 8 + k]) << 16;
            float f = fabsf(__uint_as_float(b));
            if (!(f < 1.0f)) bad = 1;
        }
        unsigned long long m = __ballot(bad);
        if (lane == 0) flag[0] = (m == 0ULL) ? 1 : 0;
    }
    __syncthreads();
    int base = blockIdx.x * CHUNK;
    int n = N_EDGES - base; if (n > CHUNK) n = CHUNK;
    const int4* d4p = (const int4*)(dst + base);   // base multiple of 4096 -> 16B aligned
    int n4 = n >> 2;
    for (int i = threadIdx.x; i < n4; i += blockDim.x) {
        int4 d = d4p[i];
        atomicAdd(&h[d.x >> BSHIFT], 1);
        atomicAdd(&h[d.y >> BSHIFT], 1);
        atomicAdd(&h[d.z >> BSHIFT], 1);
        atomicAdd(&h[d.w >> BSHIFT], 1);
    }
    for (int i = (n4 << 2) + (int)threadIdx.x; i < n; i += blockDim.x)
        atomicAdd(&h[dst[base + i] >> BSHIFT], 1);
    __syncthreads();
    for (int b = threadIdx.x; b < NBUCKET; b += blockDim.x) {
        int c = h[b];
        M[blockIdx.x * NBUCKET + b] = c;
        if (c) atomicAdd(&tot[b], c);
    }
}

// ---- stage 2: exclusive scan of 245 bucket totals; seed reservation cursors ----
__global__ void scan_bbase(const int* __restrict__ tot, int* __restrict__ bbase,
                           int* __restrict__ gres, int* __restrict__ row_ptr) {
    __shared__ int sh[256];
    int b = threadIdx.x;
    int v = (b < NBUCKET) ? tot[b] : 0;
    sh[b] = v;
    __syncthreads();
    for (int off = 1; off < 256; off <<= 1) {
        int t = (b >= off) ? sh[b - off] : 0;
        __syncthreads();
        sh[b] += t;
        __syncthreads();
    }
    if (b < NBUCKET) {
        int ex = sh[b] - v;
        bbase[b] = ex;
        gres[b]  = ex;
    }
    if (b == 0) { bbase[NBUCKET] = N_EDGES; row_ptr[N_NODES] = N_EDGES; }
}

// ---- stage 3: chunk sort in LDS, then line-granular coalesced flush (int4 reads) ----
__global__ void bin_scatter(const int* __restrict__ src, const int* __restrict__ dst,
                            const void* __restrict__ valsv, const int* __restrict__ flag,
                            const int* __restrict__ M, int* __restrict__ gres,
                            int2* __restrict__ aux) {
    __shared__ int  gb[NBUCKET];     // (global base - local base) per bucket
    __shared__ int  lcur[NBUCKET];   // running cursor
    __shared__ int  sc[256];         // scan temp
    __shared__ int2 stage[CHUNK];    // 32 KB staged records
    __shared__ unsigned short sb[CHUNK];  // 8 KB bucket id per slot
    int tid = threadIdx.x;
    int base = blockIdx.x * CHUNK;
    int n = N_EDGES - base; if (n > CHUNK) n = CHUNK;

    int v = (tid < NBUCKET) ? M[blockIdx.x * NBUCKET + tid] : 0;
    sc[tid] = v;
    __syncthreads();
    for (int off = 1; off < 256; off <<= 1) {
        int t = (tid >= off) ? sc[tid - off] : 0;
        __syncthreads();
        sc[tid] += t;
        __syncthreads();
    }
    if (tid < NBUCKET) {
        int lb = sc[tid] - v;                 // local exclusive base
        lcur[tid] = lb;
        gb[tid] = v ? (atomicAdd(&gres[tid], v) - lb) : 0;  // flush addr = gb[b] + j
    }
    __syncthreads();

    const int isbf = *flag;
    const int4* d4p = (const int4*)(dst + base);
    const int4* s4p = (const int4*)(src + base);
    int n4 = n >> 2;
    for (int i = tid; i < n4; i += 256) {
        int4 d = d4p[i];
        int4 s = s4p[i];
        float v0, v1, v2, v3;
        if (isbf) {
            uint2 u = ((const uint2*)valsv)[(base >> 2) + i];
            v0 = bflo(u.x); v1 = bfhi(u.x); v2 = bflo(u.y); v3 = bfhi(u.y);
        } else {
            float4 f = ((const float4*)valsv)[(base >> 2) + i];
            v0 = f.x; v1 = f.y; v2 = f.z; v3 = f.w;
        }
        int b0 = d.x >> BSHIFT, b1 = d.y >> BSHIFT, b2 = d.z >> BSHIFT, b3 = d.w >> BSHIFT;
        int p0 = atomicAdd(&lcur[b0], 1);
        int p1 = atomicAdd(&lcur[b1], 1);
        int p2 = atomicAdd(&lcur[b2], 1);
        int p3 = atomicAdd(&lcur[b3], 1);
        int2 r;
        r.x = s.x | ((d.x & (BNODES - 1)) << 18); r.y = __float_as_int(v0);
        stage[p0] = r; sb[p0] = (unsigned short)b0;
        r.x = s.y | ((d.y & (BNODES - 1)) << 18); r.y = __float_as_int(v1);
        stage[p1] = r; sb[p1] = (unsigned short)b1;
        r.x = s.z | ((d.z & (BNODES - 1)) << 18); r.y = __float_as_int(v2);
        stage[p2] = r; sb[p2] = (unsigned short)b2;
        r.x = s.w | ((d.w & (BNODES - 1)) << 18); r.y = __float_as_int(v3);
        stage[p3] = r; sb[p3] = (unsigned short)b3;
    }
    for (int i = (n4 << 2) + tid; i < n; i += 256) {
        int e = base + i;
        int d = dst[e];
        int b = d >> BSHIFT;
        int pos = atomicAdd(&lcur[b], 1);
        float vv = isbf ? __bfloat162float(((const __hip_bfloat16*)valsv)[e])
                        : ((const float*)valsv)[e];
        int2 r;
        r.x = src[e] | ((d & (BNODES - 1)) << 18);
        r.y = __float_as_int(vv);
        stage[pos] = r;
        sb[pos] = (unsigned short)b;
    }
    __syncthreads();
    for (int j = tid; j < n; j += 256) {
        int b = sb[j];
        aux[gb[b] + j] = stage[j];   // consecutive j within a run -> consecutive addrs
    }
}

// ---- stage 4: one block per bucket (1024 nodes): row_ptr slice + packed sedge ----
__global__ void bucket_csr(const int* __restrict__ bbase, const int2* __restrict__ aux,
                           int* __restrict__ row_ptr, int2* __restrict__ sedge) {
    __shared__ int h[BNODES];
    __shared__ int c[BNODES];
    int b  = blockIdx.x;
    int n0 = b << BSHIFT;
    int nd = N_NODES - n0; if (nd > BNODES) nd = BNODES;
    int lo = bbase[b], hi = bbase[b + 1];
    int t = threadIdx.x;
    h[t] = 0;
    __syncthreads();
    if (hi > lo) {
        int lo2 = (lo + 1) & ~1;              // first even index >= lo
        if (t == 0 && lo < lo2)
            atomicAdd(&h[(aux[lo].x >> 18) & (BNODES - 1)], 1);
        int np = (hi - lo2) >> 1;             // full int2-pairs
        const int4* ap = (const int4*)aux;    // 2 records per int4
        for (int i = t; i < np; i += BNODES) {
            int4 two = ap[(lo2 >> 1) + i];
            atomicAdd(&h[(two.x >> 18) & (BNODES - 1)], 1);
            atomicAdd(&h[(two.z >> 18) & (BNODES - 1)], 1);
        }
        int rem = lo2 + (np << 1);
        if (t == 0 && rem < hi)
            atomicAdd(&h[(aux[rem].x >> 18) & (BNODES - 1)], 1);
    }
    __syncthreads();
    int v = h[t];
    c[t] = v;
    __syncthreads();
    for (int off = 1; off < BNODES; off <<= 1) {
        int u = (t >= off) ? c[t - off] : 0;
        __syncthreads();
        c[t] += u;
        __syncthreads();
    }
    int gbase = lo + c[t] - v;            // exclusive prefix + bucket base
    if (t < nd) row_ptr[n0 + t] = gbase;
    c[t] = gbase;                         // reuse as cursor
    __syncthreads();
    for (int e = lo + t; e < hi; e += blockDim.x) {
        int2 r = aux[e];
        int pos = atomicAdd(&c[(r.x >> 18) & (BNODES - 1)], 1);
        int2 o; o.x = r.x & 0x3FFFF; o.y = r.y;
        sedge[pos] = o;
    }
}

// ---------------- init: x0(f16) = concat(user,item); T2 also seeds out ----------------
__global__ void init_kernel(const void* __restrict__ uev, const void* __restrict__ iev,
                            const int* __restrict__ flag,
                            unsigned int* __restrict__ x,     // f16 pairs
                            void* __restrict__ outacc) {      // T2 only (may be null)
    int i4 = blockIdx.x * blockDim.x + threadIdx.x;
    if (i4 >= N_ELEM / 4) return;
    const int isbf = *flag;
    float v0, v1, v2, v3;
    if (i4 < U_ELEM / 4) {
        if (isbf) {
            uint2 u = ((const uint2*)uev)[i4];
            v0 = bflo(u.x); v1 = bfhi(u.x); v2 = bflo(u.y); v3 = bfhi(u.y);
        } else {
            float4 f = ((const float4*)uev)[i4];
            v0 = f.x; v1 = f.y; v2 = f.z; v3 = f.w;
        }
    } else {
        int j4 = i4 - U_ELEM / 4;
        if (isbf) {
            uint2 u = ((const uint2*)iev)[j4];
            v0 = bflo(u.x); v1 = bfhi(u.x); v2 = bflo(u.y); v3 = bfhi(u.y);
        } else {
            float4 f = ((const float4*)iev)[j4];
            v0 = f.x; v1 = f.y; v2 = f.z; v3 = f.w;
        }
    }
    uint2 pv; pv.x = pkh(v0, v1); pv.y = pkh(v2, v3);   // f16 storage
    ((uint2*)x)[i4] = pv;
    if (outacc) {
        if (isbf) {
            uint2 o; o.x = pk(0.25f * v0, 0.25f * v1); o.y = pk(0.25f * v2, 0.25f * v3);
            ((uint2*)outacc)[i4] = o;
        } else {
            float4 f; f.x = 0.25f * v0; f.y = 0.25f * v1; f.z = 0.25f * v2; f.w = 0.25f * v3;
            ((float4*)outacc)[i4] = f;
        }
    }
}

// ---------------- CSR SpMM: one wave per dst node, flat 4-group issue ----------------
// Stream operands (sedge, p0/p1, out RMW, xn store) use nontemporal hints so the
// L2s retain the gather table x. The c = x[oq] read in MODE1 stays cached (x is the
// live gather table).
// MODE 0: T1 mid   -> xn = f16(s)
// MODE 1: T1 last  -> out = 0.25*(x0+x1+x2+s)
// MODE 2: T2 mid   -> xn = f16(s); out += 0.25*s (RMW)
// MODE 3: T2 last  -> out += 0.25*s (RMW)
template <int MODE>
__global__ void spmm_csr(const int* __restrict__ row_ptr,
                         const int2* __restrict__ sedge,
                         const unsigned int* __restrict__ x,   // f16 pairs
                         unsigned int* __restrict__ xn,        // f16 pairs
                         const unsigned int* __restrict__ p0,  // f16 pairs
                         const unsigned int* __restrict__ p1,  // f16 pairs
                         void* __restrict__ outv,
                         const int* __restrict__ flag) {
    int lane = threadIdx.x & 63;
    int g = lane >> 3;          // edge slot 0..7
    int q16 = (lane & 7) << 4;  // byte offset of dim octet within row (q*16)
    int w = (blockIdx.x * blockDim.x + threadIdx.x) >> 6;
    if (w >= N_NODES) return;
    const int isbf = *flag;
    int beg = row_ptr[w], end = row_ptr[w + 1];

    const char* xb = (const char*)x;     // row stride 128 B (64 f16)
    float s0 = 0.f, s1 = 0.f, s2 = 0.f, s3 = 0.f, s4 = 0.f, s5 = 0.f, s6 = 0.f, s7 = 0.f;
    float t0 = 0.f, t1 = 0.f, t2 = 0.f, t3 = 0.f, t4 = 0.f, t5 = 0.f, t6 = 0.f, t7 = 0.f;

    if (beg < end) {
        int em1 = end - 1;
        int e0 = beg + g, e1 = beg + 8 + g, e2 = beg + 16 + g, e3 = beg + 24 + g;
        // 4 independent sedge loads (clamped), nontemporal
        int2 r0 = ldnt2(&sedge[e0 <= em1 ? e0 : em1]);
        int2 r1 = ldnt2(&sedge[e1 <= em1 ? e1 : em1]);
        int2 r2 = ldnt2(&sedge[e2 <= em1 ? e2 : em1]);
        int2 r3 = ldnt2(&sedge[e3 <= em1 ? e3 : em1]);
        // 4 independent row gathers (cached — x reused across waves)
        uint4 v0 = *(const uint4*)(xb + ((r0.x << 7) + q16));
        uint4 v1 = *(const uint4*)(xb + ((r1.x << 7) + q16));
        uint4 v2 = *(const uint4*)(xb + ((r2.x << 7) + q16));
        uint4 v3 = *(const uint4*)(xb + ((r3.x << 7) + q16));
        float w0 = (e0 <= em1) ? __int_as_float(r0.y) : 0.f;
        float w1 = (e1 <= em1) ? __int_as_float(r1.y) : 0.f;
        float w2 = (e2 <= em1) ? __int_as_float(r2.y) : 0.f;
        float w3 = (e3 <= em1) ? __int_as_float(r3.y) : 0.f;
        {
            h2 a0 = uh(v0.x), a1 = uh(v0.y), a2 = uh(v0.z), a3 = uh(v0.w);
            s0 = fmaf((float)a0.x, w0, s0); s1 = fmaf((float)a0.y, w0, s1);
            s2 = fmaf((float)a1.x, w0, s2); s3 = fmaf((float)a1.y, w0, s3);
            s4 = fmaf((float)a2.x, w0, s4); s5 = fmaf((float)a2.y, w0, s5);
            s6 = fmaf((float)a3.x, w0, s6); s7 = fmaf((float)a3.y, w0, s7);
        }
        {
            h2 a0 = uh(v1.x), a1 = uh(v1.y), a2 = uh(v1.z), a3 = uh(v1.w);
            t0 = fmaf((float)a0.x, w1, t0); t1 = fmaf((float)a0.y, w1, t1);
            t2 = fmaf((float)a1.x, w1, t2); t3 = fmaf((float)a1.y, w1, t3);
            t4 = fmaf((float)a2.x, w1, t4); t5 = fmaf((float)a2.y, w1, t5);
            t6 = fmaf((float)a3.x, w1, t6); t7 = fmaf((float)a3.y, w1, t7);
        }
        {
            h2 a0 = uh(v2.x), a1 = uh(v2.y), a2 = uh(v2.z), a3 = uh(v2.w);
            s0 = fmaf((float)a0.x, w2, s0); s1 = fmaf((float)a0.y, w2, s1);
            s2 = fmaf((float)a1.x, w2, s2); s3 = fmaf((float)a1.y, w2, s3);
            s4 = fmaf((float)a2.x, w2, s4); s5 = fmaf((float)a2.y, w2, s5);
            s6 = fmaf((float)a3.x, w2, s6); s7 = fmaf((float)a3.y, w2, s7);
        }
        {
            h2 a0 = uh(v3.x), a1 = uh(v3.y), a2 = uh(v3.z), a3 = uh(v3.w);
            t0 = fmaf((float)a0.x, w3, t0); t1 = fmaf((float)a0.y, w3, t1);
            t2 = fmaf((float)a1.x, w3, t2); t3 = fmaf((float)a1.y, w3, t3);
            t4 = fmaf((float)a2.x, w3, t4); t5 = fmaf((float)a2.y, w3, t5);
            t6 = fmaf((float)a3.x, w3, t6); t7 = fmaf((float)a3.y, w3, t7);
        }
        // long rows (rare): clamped 16-edge steps
        for (int eb16 = beg + 32; eb16 < end; eb16 += 16) {
            int ea = eb16 + g, eb = eb16 + 8 + g;
            int2 ra = ldnt2(&sedge[ea <= em1 ? ea : em1]);
            int2 rb = ldnt2(&sedge[eb <= em1 ? eb : em1]);
            uint4 va = *(const uint4*)(xb + ((ra.x << 7) + q16));
            uint4 vb = *(const uint4*)(xb + ((rb.x << 7) + q16));
            float wa = (ea <= em1) ? __int_as_float(ra.y) : 0.f;
            float wb = (eb <= em1) ? __int_as_float(rb.y) : 0.f;
            h2 a0 = uh(va.x), a1 = uh(va.y), a2 = uh(va.z), a3 = uh(va.w);
            h2 b0 = uh(vb.x), b1 = uh(vb.y), b2 = uh(vb.z), b3 = uh(vb.w);
            s0 = fmaf((float)a0.x, wa, s0); s1 = fmaf((float)a0.y, wa, s1);
            s2 = fmaf((float)a1.x, wa, s2); s3 = fmaf((float)a1.y, wa, s3);
            s4 = fmaf((float)a2.x, wa, s4); s5 = fmaf((float)a2.y, wa, s5);
            s6 = fmaf((float)a3.x, wa, s6); s7 = fmaf((float)a3.y, wa, s7);
            t0 = fmaf((float)b0.x, wb, t0); t1 = fmaf((float)b0.y, wb, t1);
            t2 = fmaf((float)b1.x, wb, t2); t3 = fmaf((float)b1.y, wb, t3);
            t4 = fmaf((float)b2.x, wb, t4); t5 = fmaf((float)b2.y, wb, t5);
            t6 = fmaf((float)b3.x, wb, t6); t7 = fmaf((float)b3.y, wb, t7);
        }
    }
    s0 += t0; s1 += t1; s2 += t2; s3 += t3;
    s4 += t4; s5 += t5; s6 += t6; s7 += t7;

    // reduce across the 8 edge slots (lanes q, q+8, ..., q+56)
    s0 += __shfl_xor(s0, 8);  s1 += __shfl_xor(s1, 8);
    s2 += __shfl_xor(s2, 8);  s3 += __shfl_xor(s3, 8);
    s4 += __shfl_xor(s4, 8);  s5 += __shfl_xor(s5, 8);
    s6 += __shfl_xor(s6, 8);  s7 += __shfl_xor(s7, 8);
    s0 += __shfl_xor(s0, 16); s1 += __shfl_xor(s1, 16);
    s2 += __shfl_xor(s2, 16); s3 += __shfl_xor(s3, 16);
    s4 += __shfl_xor(s4, 16); s5 += __shfl_xor(s5, 16);
    s6 += __shfl_xor(s6, 16); s7 += __shfl_xor(s7, 16);
    s0 += __shfl_xor(s0, 32); s1 += __shfl_xor(s1, 32);
    s2 += __shfl_xor(s2, 32); s3 += __shfl_xor(s3, 32);
    s4 += __shfl_xor(s4, 32); s5 += __shfl_xor(s5, 32);
    s6 += __shfl_xor(s6, 32); s7 += __shfl_xor(s7, 32);

    if (g != 0) return;                  // 8 lanes carry the row (128B store)
    size_t oq = (size_t)w * 8 + (lane & 7);   // uint4 index for dims q*8..q*8+7

    if (MODE == 0) {
        uint4 pv;
        pv.x = pkh(s0, s1); pv.y = pkh(s2, s3); pv.z = pkh(s4, s5); pv.w = pkh(s6, s7);
        stnt4(&((uint4*)xn)[oq], pv);
    } else if (MODE == 1) {
        uint4 a = ldnt4(&((const uint4*)p0)[oq]);
        uint4 b = ldnt4(&((const uint4*)p1)[oq]);
        uint4 c = ((const uint4*)x)[oq];          // x == x2: live gather table, keep cached
        h2 A0 = uh(a.x), A1 = uh(a.y), A2 = uh(a.z), A3 = uh(a.w);
        h2 B0 = uh(b.x), B1 = uh(b.y), B2 = uh(b.z), B3 = uh(b.w);
        h2 C0 = uh(c.x), C1 = uh(c.y), C2 = uh(c.z), C3 = uh(c.w);
        float r0 = 0.25f * (s0 + (float)A0.x + (float)B0.x + (float)C0.x);
        float r1 = 0.25f * (s1 + (float)A0.y + (float)B0.y + (float)C0.y);
        float r2 = 0.25f * (s2 + (float)A1.x + (float)B1.x + (float)C1.x);
        float r3 = 0.25f * (s3 + (float)A1.y + (float)B1.y + (float)C1.y);
        float r4 = 0.25f * (s4 + (float)A2.x + (float)B2.x + (float)C2.x);
        float r5 = 0.25f * (s5 + (float)A2.y + (float)B2.y + (float)C2.y);
        float r6 = 0.25f * (s6 + (float)A3.x + (float)B3.x + (float)C3.x);
        float r7 = 0.25f * (s7 + (float)A3.y + (float)B3.y + (float)C3.y);
        if (isbf) {
            uint4 pv;
            pv.x = pk(r0, r1); pv.y = pk(r2, r3); pv.z = pk(r4, r5); pv.w = pk(r6, r7);
            stnt4(&((uint4*)outv)[oq], pv);
        } else {
            float4 f0; f0.x = r0; f0.y = r1; f0.z = r2; f0.w = r3;
            float4 f1; f1.x = r4; f1.y = r5; f1.z = r6; f1.w = r7;
            stnt4f(&((float4*)outv)[2 * oq], f0);
            stnt4f(&((float4*)outv)[2 * oq + 1], f1);
        }
    } else if (MODE == 2) {
        uint4 pv;
        pv.x = pkh(s0, s1); pv.y = pkh(s2, s3); pv.z = pkh(s4, s5); pv.w = pkh(s6, s7);
        stnt4(&((uint4*)xn)[oq], pv);
        if (isbf) {
            uint4 ov = ldnt4(&((uint4*)outv)[oq]);
            float r0 = bflo(ov.x) + 0.25f * s0;
            float r1 = bfhi(ov.x) + 0.25f * s1;
            float r2 = bflo(ov.y) + 0.25f * s2;
            float r3 = bfhi(ov.y) + 0.25f * s3;
            float r4 = bflo(ov.z) + 0.25f * s4;
            float r5 = bfhi(ov.z) + 0.25f * s5;
            float r6 = bflo(ov.w) + 0.25f * s6;
            float r7 = bfhi(ov.w) + 0.25f * s7;
            uint4 nv;
            nv.x = pk(r0, r1); nv.y = pk(r2, r3); nv.z = pk(r4, r5); nv.w = pk(r6, r7);
            stnt4(&((uint4*)outv)[oq], nv);
        } else {
            float4 o0 = ldnt4f(&((float4*)outv)[2 * oq]);
            float4 o1 = ldnt4f(&((float4*)outv)[2 * oq + 1]);
            o0.x += 0.25f * s0; o0.y += 0.25f * s1; o0.z += 0.25f * s2; o0.w += 0.25f * s3;
            o1.x += 0.25f * s4; o1.y += 0.25f * s5; o1.z += 0.25f * s6; o1.w += 0.25f * s7;
            stnt4f(&((float4*)outv)[2 * oq], o0);
            stnt4f(&((float4*)outv)[2 * oq + 1], o1);
        }
    } else {
        if (isbf) {
            uint4 ov = ldnt4(&((uint4*)outv)[oq]);
            float r0 = bflo(ov.x) + 0.25f * s0;
            float r1 = bfhi(ov.x) + 0.25f * s1;
            float r2 = bflo(ov.y) + 0.25f * s2;
            float r3 = bfhi(ov.y) + 0.25f * s3;
            float r4 = bflo(ov.z) + 0.25f * s4;
            float r5 = bfhi(ov.z) + 0.25f * s5;
            float r6 = bflo(ov.w) + 0.25f * s6;
            float r7 = bfhi(ov.w) + 0.25f * s7;
            uint4 nv;
            nv.x = pk(r0, r1); nv.y = pk(r2, r3); nv.z = pk(r4, r5); nv.w = pk(r6, r7);
            stnt4(&((uint4*)outv)[oq], nv);
        } else {
            float4 o0 = ldnt4f(&((float4*)outv)[2 * oq]);
            float4 o1 = ldnt4f(&((float4*)outv)[2 * oq + 1]);
            o0.x += 0.25f * s0; o0.y += 0.25f * s1; o0.z += 0.25f * s2; o0.w += 0.25f * s3;
            o1.x += 0.25f * s4; o1.y += 0.25f * s5; o1.z += 0.25f * s6; o1.w += 0.25f * s7;
            stnt4f(&((float4*)outv)[2 * oq], o0);
            stnt4f(&((float4*)outv)[2 * oq + 1], o1);
        }
    }
}

// ---------------- host ----------------
static inline size_t align256(size_t x) { return (x + 255) & ~(size_t)255; }

extern "C" void kernel_launch(void* const* d_in, const int* in_sizes, int n_in,
                              void* d_out, int out_size, void* d_ws, size_t ws_size,
                              hipStream_t stream) {
    const int* es = (const int*)d_in[3];
    const int* ed = (const int*)d_in[4];

    char* wsb = (char*)d_ws;
    size_t off = 0;
    int*  flag    = (int*)wsb;               off = align256(off + sizeof(int));
    int*  tot     = (int*)(wsb + off);       off = align256(off + (size_t)NBUCKET * 4);
    int*  bbase   = (int*)(wsb + off);       off = align256(off + (size_t)(NBUCKET + 1) * 4);
    int*  gres    = (int*)(wsb + off);       off = align256(off + (size_t)NBUCKET * 4);
    int*  M       = (int*)(wsb + off);       off = align256(off + (size_t)NB_HIST * NBUCKET * 4);
    int*  row_ptr = (int*)(wsb + off);       off = align256(off + (size_t)(N_NODES + 1) * 4);
    int2* sedge   = (int2*)(wsb + off);      off = align256(off + (size_t)N_EDGES * 8);
    size_t z_off = off;
    // aux (32 MB) aliases x0: bucket_csr consumes aux before init writes x0.
    int2* aux = (int2*)(wsb + z_off);

    const size_t hbuf = (size_t)N_ELEM * 2;   // 32 MB per f16 state buffer

    const int eb = 256;
    const int egrid = (N_ELEM / 4 + eb - 1) / eb;         // init, x4-vectorized
    const int sgrid = (N_NODES + 3) / 4;                  // 62500 blocks, 4 waves each

    // ---- build: totals(+probe fused) -> scan -> LDS-sorted binning -> bucket CSR ----
    hipMemsetAsync(tot, 0, (size_t)NBUCKET * 4, stream);
    hist_bucket<<<NB_HIST, eb, 0, stream>>>(ed, (const unsigned short*)d_in[0], flag, M, tot);
    scan_bbase<<<1, 256, 0, stream>>>(tot, bbase, gres, row_ptr);
    bin_scatter<<<NB_HIST, eb, 0, stream>>>(es, ed, d_in[2], flag, M, gres, aux);
    bucket_csr<<<NBUCKET, BNODES, 0, stream>>>(bbase, aux, row_ptr, sedge);

    size_t need_t1 = z_off + 3 * hbuf;   // ~130 MB

    if (ws_size >= need_t1) {
        // T1: f16 x0,x1,x2; last spmm fuses the 4-term average into d_out
        unsigned int* x0 = (unsigned int*)(wsb + z_off);
        unsigned int* x1 = (unsigned int*)(wsb + z_off + hbuf);
        unsigned int* x2 = (unsigned int*)(wsb + z_off + 2 * hbuf);
        init_kernel<<<egrid, eb, 0, stream>>>(d_in[0], d_in[1], flag, x0, nullptr);
        spmm_csr<0><<<sgrid, eb, 0, stream>>>(row_ptr, sedge, x0, x1, nullptr, nullptr, nullptr, flag);
        spmm_csr<0><<<sgrid, eb, 0, stream>>>(row_ptr, sedge, x1, x2, nullptr, nullptr, nullptr, flag);
        spmm_csr<1><<<sgrid, eb, 0, stream>>>(row_ptr, sedge, x2, nullptr, x0, x1, d_out, flag);
    } else {
        // T2: f16 x, xn; accumulate into d_out (RMW)
        unsigned int* x  = (unsigned int*)(wsb + z_off);
        unsigned int* xn = (unsigned int*)(wsb + z_off + hbuf);
        init_kernel<<<egrid, eb, 0, stream>>>(d_in[0], d_in[1], flag, x, d_out);
        spmm_csr<2><<<sgrid, eb, 0, stream>>>(row_ptr, sedge, x,  xn, nullptr, nullptr, d_out, flag);
        spmm_csr<2><<<sgrid, eb, 0, stream>>>(row_ptr, sedge, xn, x,  nullptr, nullptr, d_out, flag);
        spmm_csr<3><<<sgrid, eb, 0, stream>>>(row_ptr, sedge, x,  nullptr, nullptr, nullptr, d_out, flag);
    }
}

// Round 11
// 522.546 us; speedup vs baseline: 1.0703x; 1.0703x over previous
//
#include <hip/hip_runtime.h>
#include <hip/hip_bf16.h>

#define N_USERS 100000
#define N_ITEMS 150000
#define N_NODES 250000
#define N_EDGES 4000000
#define DIM     64
#define N_ELEM  (N_NODES * DIM)      // 16,000,000
#define U_ELEM  (N_USERS * DIM)      //  6,400,000
#define BSHIFT  10
#define BNODES  (1 << BSHIFT)        // 1024 nodes per bucket
#define NBUCKET ((N_NODES + BNODES - 1) >> BSHIFT)   // 245
#define CHUNK   4096
#define NB_HIST ((N_EDGES + CHUNK - 1) / CHUNK)      // 977

typedef _Float16 h2 __attribute__((ext_vector_type(2)));

// ---------------- bf16 helpers (bit-level, RNE pack) ----------------
__device__ __forceinline__ float bflo(unsigned int u) { return __uint_as_float(u << 16); }
__device__ __forceinline__ float bfhi(unsigned int u) { return __uint_as_float(u & 0xffff0000u); }
__device__ __forceinline__ unsigned int bfr(float f) {   // f32 -> bf16 bits, round-nearest-even
    unsigned int u = __float_as_uint(f);
    return (u + 0x7fffu + ((u >> 16) & 1u)) >> 16;
}
__device__ __forceinline__ unsigned int pk(float a, float b) {  // two bf16 packed, a in low half
    return bfr(a) | (bfr(b) << 16);
}
// ---------------- f16 helpers (half2-in-uint) ----------------
__device__ __forceinline__ h2 uh(unsigned int u) {
    union { unsigned int u; h2 h; } c; c.u = u; return c.h;
}
__device__ __forceinline__ unsigned int pkh(float a, float b) {  // two f16 packed
    union { h2 h; unsigned int u; } c;
    c.h.x = (_Float16)a; c.h.y = (_Float16)b;
    return c.u;
}

// ---- stage 1: per-chunk bucket histogram (int4 reads) + probe fused into block 0 ----
__global__ void hist_bucket(const int* __restrict__ dst, const unsigned short* __restrict__ ue,
                            int* __restrict__ flag, int* __restrict__ M,
                            int* __restrict__ tot) {
    __shared__ int h[NBUCKET];
    for (int b = threadIdx.x; b < NBUCKET; b += blockDim.x) h[b] = 0;
    if (blockIdx.x == 0 && threadIdx.x < 64) {   // dtype probe (wave 0 of block 0)
        int lane = threadIdx.x;
        int bad = 0;
        #pragma unroll
        for (int k = 0; k < 8; ++k) {
            unsigned int b = ((unsigned int)ue[lane * 8 + k]) << 16;
            float f = fabsf(__uint_as_float(b));
            if (!(f < 1.0f)) bad = 1;
        }
        unsigned long long m = __ballot(bad);
        if (lane == 0) flag[0] = (m == 0ULL) ? 1 : 0;
    }
    __syncthreads();
    int base = blockIdx.x * CHUNK;
    int n = N_EDGES - base; if (n > CHUNK) n = CHUNK;
    const int4* d4p = (const int4*)(dst + base);   // base multiple of 4096 -> 16B aligned
    int n4 = n >> 2;
    for (int i = threadIdx.x; i < n4; i += blockDim.x) {
        int4 d = d4p[i];
        atomicAdd(&h[d.x >> BSHIFT], 1);
        atomicAdd(&h[d.y >> BSHIFT], 1);
        atomicAdd(&h[d.z >> BSHIFT], 1);
        atomicAdd(&h[d.w >> BSHIFT], 1);
    }
    for (int i = (n4 << 2) + (int)threadIdx.x; i < n; i += blockDim.x)
        atomicAdd(&h[dst[base + i] >> BSHIFT], 1);
    __syncthreads();
    for (int b = threadIdx.x; b < NBUCKET; b += blockDim.x) {
        int c = h[b];
        M[blockIdx.x * NBUCKET + b] = c;
        if (c) atomicAdd(&tot[b], c);
    }
}

// ---- stage 2: exclusive scan of 245 bucket totals; seed reservation cursors ----
__global__ void scan_bbase(const int* __restrict__ tot, int* __restrict__ bbase,
                           int* __restrict__ gres, int* __restrict__ row_ptr) {
    __shared__ int sh[256];
    int b = threadIdx.x;
    int v = (b < NBUCKET) ? tot[b] : 0;
    sh[b] = v;
    __syncthreads();
    for (int off = 1; off < 256; off <<= 1) {
        int t = (b >= off) ? sh[b - off] : 0;
        __syncthreads();
        sh[b] += t;
        __syncthreads();
    }
    if (b < NBUCKET) {
        int ex = sh[b] - v;
        bbase[b] = ex;
        gres[b]  = ex;
    }
    if (b == 0) { bbase[NBUCKET] = N_EDGES; row_ptr[N_NODES] = N_EDGES; }
}

// ---- stage 3: chunk sort in LDS, then line-granular coalesced flush (int4 reads) ----
__global__ void bin_scatter(const int* __restrict__ src, const int* __restrict__ dst,
                            const void* __restrict__ valsv, const int* __restrict__ flag,
                            const int* __restrict__ M, int* __restrict__ gres,
                            int2* __restrict__ aux) {
    __shared__ int  gb[NBUCKET];     // (global base - local base) per bucket
    __shared__ int  lcur[NBUCKET];   // running cursor
    __shared__ int  sc[256];         // scan temp
    __shared__ int2 stage[CHUNK];    // 32 KB staged records
    __shared__ unsigned short sb[CHUNK];  // 8 KB bucket id per slot
    int tid = threadIdx.x;
    int base = blockIdx.x * CHUNK;
    int n = N_EDGES - base; if (n > CHUNK) n = CHUNK;

    int v = (tid < NBUCKET) ? M[blockIdx.x * NBUCKET + tid] : 0;
    sc[tid] = v;
    __syncthreads();
    for (int off = 1; off < 256; off <<= 1) {
        int t = (tid >= off) ? sc[tid - off] : 0;
        __syncthreads();
        sc[tid] += t;
        __syncthreads();
    }
    if (tid < NBUCKET) {
        int lb = sc[tid] - v;                 // local exclusive base
        lcur[tid] = lb;
        gb[tid] = v ? (atomicAdd(&gres[tid], v) - lb) : 0;  // flush addr = gb[b] + j
    }
    __syncthreads();

    const int isbf = *flag;
    const int4* d4p = (const int4*)(dst + base);
    const int4* s4p = (const int4*)(src + base);
    int n4 = n >> 2;
    for (int i = tid; i < n4; i += 256) {
        int4 d = d4p[i];
        int4 s = s4p[i];
        float v0, v1, v2, v3;
        if (isbf) {
            uint2 u = ((const uint2*)valsv)[(base >> 2) + i];
            v0 = bflo(u.x); v1 = bfhi(u.x); v2 = bflo(u.y); v3 = bfhi(u.y);
        } else {
            float4 f = ((const float4*)valsv)[(base >> 2) + i];
            v0 = f.x; v1 = f.y; v2 = f.z; v3 = f.w;
        }
        int b0 = d.x >> BSHIFT, b1 = d.y >> BSHIFT, b2 = d.z >> BSHIFT, b3 = d.w >> BSHIFT;
        int p0 = atomicAdd(&lcur[b0], 1);
        int p1 = atomicAdd(&lcur[b1], 1);
        int p2 = atomicAdd(&lcur[b2], 1);
        int p3 = atomicAdd(&lcur[b3], 1);
        int2 r;
        r.x = s.x | ((d.x & (BNODES - 1)) << 18); r.y = __float_as_int(v0);
        stage[p0] = r; sb[p0] = (unsigned short)b0;
        r.x = s.y | ((d.y & (BNODES - 1)) << 18); r.y = __float_as_int(v1);
        stage[p1] = r; sb[p1] = (unsigned short)b1;
        r.x = s.z | ((d.z & (BNODES - 1)) << 18); r.y = __float_as_int(v2);
        stage[p2] = r; sb[p2] = (unsigned short)b2;
        r.x = s.w | ((d.w & (BNODES - 1)) << 18); r.y = __float_as_int(v3);
        stage[p3] = r; sb[p3] = (unsigned short)b3;
    }
    for (int i = (n4 << 2) + tid; i < n; i += 256) {
        int e = base + i;
        int d = dst[e];
        int b = d >> BSHIFT;
        int pos = atomicAdd(&lcur[b], 1);
        float vv = isbf ? __bfloat162float(((const __hip_bfloat16*)valsv)[e])
                        : ((const float*)valsv)[e];
        int2 r;
        r.x = src[e] | ((d & (BNODES - 1)) << 18);
        r.y = __float_as_int(vv);
        stage[pos] = r;
        sb[pos] = (unsigned short)b;
    }
    __syncthreads();
    for (int j = tid; j < n; j += 256) {
        int b = sb[j];
        aux[gb[b] + j] = stage[j];   // consecutive j within a run -> consecutive addrs
    }
}

// ---- stage 4: one block per bucket (1024 nodes): row_ptr slice + packed sedge ----
__global__ void bucket_csr(const int* __restrict__ bbase, const int2* __restrict__ aux,
                           int* __restrict__ row_ptr, int2* __restrict__ sedge) {
    __shared__ int h[BNODES];
    __shared__ int c[BNODES];
    int b  = blockIdx.x;
    int n0 = b << BSHIFT;
    int nd = N_NODES - n0; if (nd > BNODES) nd = BNODES;
    int lo = bbase[b], hi = bbase[b + 1];
    int t = threadIdx.x;
    h[t] = 0;
    __syncthreads();
    if (hi > lo) {
        int lo2 = (lo + 1) & ~1;              // first even index >= lo
        if (t == 0 && lo < lo2)
            atomicAdd(&h[(aux[lo].x >> 18) & (BNODES - 1)], 1);
        int np = (hi - lo2) >> 1;             // full int2-pairs
        const int4* ap = (const int4*)aux;    // 2 records per int4
        for (int i = t; i < np; i += BNODES) {
            int4 two = ap[(lo2 >> 1) + i];
            atomicAdd(&h[(two.x >> 18) & (BNODES - 1)], 1);
            atomicAdd(&h[(two.z >> 18) & (BNODES - 1)], 1);
        }
        int rem = lo2 + (np << 1);
        if (t == 0 && rem < hi)
            atomicAdd(&h[(aux[rem].x >> 18) & (BNODES - 1)], 1);
    }
    __syncthreads();
    int v = h[t];
    c[t] = v;
    __syncthreads();
    for (int off = 1; off < BNODES; off <<= 1) {
        int u = (t >= off) ? c[t - off] : 0;
        __syncthreads();
        c[t] += u;
        __syncthreads();
    }
    int gbase = lo + c[t] - v;            // exclusive prefix + bucket base
    if (t < nd) row_ptr[n0 + t] = gbase;
    c[t] = gbase;                         // reuse as cursor
    __syncthreads();
    for (int e = lo + t; e < hi; e += blockDim.x) {
        int2 r = aux[e];
        int pos = atomicAdd(&c[(r.x >> 18) & (BNODES - 1)], 1);
        int2 o; o.x = r.x & 0x3FFFF; o.y = r.y;
        sedge[pos] = o;
    }
}

// ---------------- init: x0(f16) = concat(user,item); T2 also seeds out ----------------
__global__ void init_kernel(const void* __restrict__ uev, const void* __restrict__ iev,
                            const int* __restrict__ flag,
                            unsigned int* __restrict__ x,     // f16 pairs
                            void* __restrict__ outacc) {      // T2 only (may be null)
    int i4 = blockIdx.x * blockDim.x + threadIdx.x;
    if (i4 >= N_ELEM / 4) return;
    const int isbf = *flag;
    float v0, v1, v2, v3;
    if (i4 < U_ELEM / 4) {
        if (isbf) {
            uint2 u = ((const uint2*)uev)[i4];
            v0 = bflo(u.x); v1 = bfhi(u.x); v2 = bflo(u.y); v3 = bfhi(u.y);
        } else {
            float4 f = ((const float4*)uev)[i4];
            v0 = f.x; v1 = f.y; v2 = f.z; v3 = f.w;
        }
    } else {
        int j4 = i4 - U_ELEM / 4;
        if (isbf) {
            uint2 u = ((const uint2*)iev)[j4];
            v0 = bflo(u.x); v1 = bfhi(u.x); v2 = bflo(u.y); v3 = bfhi(u.y);
        } else {
            float4 f = ((const float4*)iev)[j4];
            v0 = f.x; v1 = f.y; v2 = f.z; v3 = f.w;
        }
    }
    uint2 pv; pv.x = pkh(v0, v1); pv.y = pkh(v2, v3);   // f16 storage
    ((uint2*)x)[i4] = pv;
    if (outacc) {
        if (isbf) {
            uint2 o; o.x = pk(0.25f * v0, 0.25f * v1); o.y = pk(0.25f * v2, 0.25f * v3);
            ((uint2*)outacc)[i4] = o;
        } else {
            float4 f; f.x = 0.25f * v0; f.y = 0.25f * v1; f.z = 0.25f * v2; f.w = 0.25f * v3;
            ((float4*)outacc)[i4] = f;
        }
    }
}

// ---------------- CSR SpMM: one wave per dst node, flat 4-group issue ----------------
// Plain cached loads/stores throughout (R10's nontemporal experiment regressed:
// nt bypasses L2 buffering -> stream BW dropped 3.2->2.8 TB/s for a 2% FETCH saving).
// MODE 0: T1 mid   -> xn = f16(s)
// MODE 1: T1 last  -> out = 0.25*(x0+x1+x2+s)
// MODE 2: T2 mid   -> xn = f16(s); out += 0.25*s (RMW)
// MODE 3: T2 last  -> out += 0.25*s (RMW)
template <int MODE>
__global__ void spmm_csr(const int* __restrict__ row_ptr,
                         const int2* __restrict__ sedge,
                         const unsigned int* __restrict__ x,   // f16 pairs
                         unsigned int* __restrict__ xn,        // f16 pairs
                         const unsigned int* __restrict__ p0,  // f16 pairs
                         const unsigned int* __restrict__ p1,  // f16 pairs
                         void* __restrict__ outv,
                         const int* __restrict__ flag) {
    int lane = threadIdx.x & 63;
    int g = lane >> 3;          // edge slot 0..7
    int q16 = (lane & 7) << 4;  // byte offset of dim octet within row (q*16)
    int w = (blockIdx.x * blockDim.x + threadIdx.x) >> 6;
    if (w >= N_NODES) return;
    const int isbf = *flag;
    int beg = row_ptr[w], end = row_ptr[w + 1];

    const char* xb = (const char*)x;     // row stride 128 B (64 f16)
    float s0 = 0.f, s1 = 0.f, s2 = 0.f, s3 = 0.f, s4 = 0.f, s5 = 0.f, s6 = 0.f, s7 = 0.f;
    float t0 = 0.f, t1 = 0.f, t2 = 0.f, t3 = 0.f, t4 = 0.f, t5 = 0.f, t6 = 0.f, t7 = 0.f;

    if (beg < end) {
        int em1 = end - 1;
        int e0 = beg + g, e1 = beg + 8 + g, e2 = beg + 16 + g, e3 = beg + 24 + g;
        // 4 independent sedge loads (clamped)
        int2 r0 = sedge[e0 <= em1 ? e0 : em1];
        int2 r1 = sedge[e1 <= em1 ? e1 : em1];
        int2 r2 = sedge[e2 <= em1 ? e2 : em1];
        int2 r3 = sedge[e3 <= em1 ? e3 : em1];
        // 4 independent row gathers, all in flight before first use
        uint4 v0 = *(const uint4*)(xb + ((r0.x << 7) + q16));
        uint4 v1 = *(const uint4*)(xb + ((r1.x << 7) + q16));
        uint4 v2 = *(const uint4*)(xb + ((r2.x << 7) + q16));
        uint4 v3 = *(const uint4*)(xb + ((r3.x << 7) + q16));
        float w0 = (e0 <= em1) ? __int_as_float(r0.y) : 0.f;
        float w1 = (e1 <= em1) ? __int_as_float(r1.y) : 0.f;
        float w2 = (e2 <= em1) ? __int_as_float(r2.y) : 0.f;
        float w3 = (e3 <= em1) ? __int_as_float(r3.y) : 0.f;
        {
            h2 a0 = uh(v0.x), a1 = uh(v0.y), a2 = uh(v0.z), a3 = uh(v0.w);
            s0 = fmaf((float)a0.x, w0, s0); s1 = fmaf((float)a0.y, w0, s1);
            s2 = fmaf((float)a1.x, w0, s2); s3 = fmaf((float)a1.y, w0, s3);
            s4 = fmaf((float)a2.x, w0, s4); s5 = fmaf((float)a2.y, w0, s5);
            s6 = fmaf((float)a3.x, w0, s6); s7 = fmaf((float)a3.y, w0, s7);
        }
        {
            h2 a0 = uh(v1.x), a1 = uh(v1.y), a2 = uh(v1.z), a3 = uh(v1.w);
            t0 = fmaf((float)a0.x, w1, t0); t1 = fmaf((float)a0.y, w1, t1);
            t2 = fmaf((float)a1.x, w1, t2); t3 = fmaf((float)a1.y, w1, t3);
            t4 = fmaf((float)a2.x, w1, t4); t5 = fmaf((float)a2.y, w1, t5);
            t6 = fmaf((float)a3.x, w1, t6); t7 = fmaf((float)a3.y, w1, t7);
        }
        {
            h2 a0 = uh(v2.x), a1 = uh(v2.y), a2 = uh(v2.z), a3 = uh(v2.w);
            s0 = fmaf((float)a0.x, w2, s0); s1 = fmaf((float)a0.y, w2, s1);
            s2 = fmaf((float)a1.x, w2, s2); s3 = fmaf((float)a1.y, w2, s3);
            s4 = fmaf((float)a2.x, w2, s4); s5 = fmaf((float)a2.y, w2, s5);
            s6 = fmaf((float)a3.x, w2, s6); s7 = fmaf((float)a3.y, w2, s7);
        }
        {
            h2 a0 = uh(v3.x), a1 = uh(v3.y), a2 = uh(v3.z), a3 = uh(v3.w);
            t0 = fmaf((float)a0.x, w3, t0); t1 = fmaf((float)a0.y, w3, t1);
            t2 = fmaf((float)a1.x, w3, t2); t3 = fmaf((float)a1.y, w3, t3);
            t4 = fmaf((float)a2.x, w3, t4); t5 = fmaf((float)a2.y, w3, t5);
            t6 = fmaf((float)a3.x, w3, t6); t7 = fmaf((float)a3.y, w3, t7);
        }
        // long rows (rare): clamped 16-edge steps
        for (int eb16 = beg + 32; eb16 < end; eb16 += 16) {
            int ea = eb16 + g, eb = eb16 + 8 + g;
            int2 ra = sedge[ea <= em1 ? ea : em1];
            int2 rb = sedge[eb <= em1 ? eb : em1];
            uint4 va = *(const uint4*)(xb + ((ra.x << 7) + q16));
            uint4 vb = *(const uint4*)(xb + ((rb.x << 7) + q16));
            float wa = (ea <= em1) ? __int_as_float(ra.y) : 0.f;
            float wb = (eb <= em1) ? __int_as_float(rb.y) : 0.f;
            h2 a0 = uh(va.x), a1 = uh(va.y), a2 = uh(va.z), a3 = uh(va.w);
            h2 b0 = uh(vb.x), b1 = uh(vb.y), b2 = uh(vb.z), b3 = uh(vb.w);
            s0 = fmaf((float)a0.x, wa, s0); s1 = fmaf((float)a0.y, wa, s1);
            s2 = fmaf((float)a1.x, wa, s2); s3 = fmaf((float)a1.y, wa, s3);
            s4 = fmaf((float)a2.x, wa, s4); s5 = fmaf((float)a2.y, wa, s5);
            s6 = fmaf((float)a3.x, wa, s6); s7 = fmaf((float)a3.y, wa, s7);
            t0 = fmaf((float)b0.x, wb, t0); t1 = fmaf((float)b0.y, wb, t1);
            t2 = fmaf((float)b1.x, wb, t2); t3 = fmaf((float)b1.y, wb, t3);
            t4 = fmaf((float)b2.x, wb, t4); t5 = fmaf((float)b2.y, wb, t5);
            t6 = fmaf((float)b3.x, wb, t6); t7 = fmaf((float)b3.y, wb, t7);
        }
    }
    s0 += t0; s1 += t1; s2 += t2; s3 += t3;
    s4 += t4; s5 += t5; s6 += t6; s7 += t7;

    // reduce across the 8 edge slots (lanes q, q+8, ..., q+56)
    s0 += __shfl_xor(s0, 8);  s1 += __shfl_xor(s1, 8);
    s2 += __shfl_xor(s2, 8);  s3 += __shfl_xor(s3, 8);
    s4 += __shfl_xor(s4, 8);  s5 += __shfl_xor(s5, 8);
    s6 += __shfl_xor(s6, 8);  s7 += __shfl_xor(s7, 8);
    s0 += __shfl_xor(s0, 16); s1 += __shfl_xor(s1, 16);
    s2 += __shfl_xor(s2, 16); s3 += __shfl_xor(s3, 16);
    s4 += __shfl_xor(s4, 16); s5 += __shfl_xor(s5, 16);
    s6 += __shfl_xor(s6, 16); s7 += __shfl_xor(s7, 16);
    s0 += __shfl_xor(s0, 32); s1 += __shfl_xor(s1, 32);
    s2 += __shfl_xor(s2, 32); s3 += __shfl_xor(s3, 32);
    s4 += __shfl_xor(s4, 32); s5 += __shfl_xor(s5, 32);
    s6 += __shfl_xor(s6, 32); s7 += __shfl_xor(s7, 32);

    if (g != 0) return;                  // 8 lanes carry the row (128B store)
    size_t oq = (size_t)w * 8 + (lane & 7);   // uint4 index for dims q*8..q*8+7

    if (MODE == 0) {
        uint4 pv;
        pv.x = pkh(s0, s1); pv.y = pkh(s2, s3); pv.z = pkh(s4, s5); pv.w = pkh(s6, s7);
        ((uint4*)xn)[oq] = pv;
    } else if (MODE == 1) {
        uint4 a = ((const uint4*)p0)[oq];
        uint4 b = ((const uint4*)p1)[oq];
        uint4 c = ((const uint4*)x)[oq];          // x == x2 here
        h2 A0 = uh(a.x), A1 = uh(a.y), A2 = uh(a.z), A3 = uh(a.w);
        h2 B0 = uh(b.x), B1 = uh(b.y), B2 = uh(b.z), B3 = uh(b.w);
        h2 C0 = uh(c.x), C1 = uh(c.y), C2 = uh(c.z), C3 = uh(c.w);
        float r0 = 0.25f * (s0 + (float)A0.x + (float)B0.x + (float)C0.x);
        float r1 = 0.25f * (s1 + (float)A0.y + (float)B0.y + (float)C0.y);
        float r2 = 0.25f * (s2 + (float)A1.x + (float)B1.x + (float)C1.x);
        float r3 = 0.25f * (s3 + (float)A1.y + (float)B1.y + (float)C1.y);
        float r4 = 0.25f * (s4 + (float)A2.x + (float)B2.x + (float)C2.x);
        float r5 = 0.25f * (s5 + (float)A2.y + (float)B2.y + (float)C2.y);
        float r6 = 0.25f * (s6 + (float)A3.x + (float)B3.x + (float)C3.x);
        float r7 = 0.25f * (s7 + (float)A3.y + (float)B3.y + (float)C3.y);
        if (isbf) {
            uint4 pv;
            pv.x = pk(r0, r1); pv.y = pk(r2, r3); pv.z = pk(r4, r5); pv.w = pk(r6, r7);
            ((uint4*)outv)[oq] = pv;
        } else {
            float4 f0; f0.x = r0; f0.y = r1; f0.z = r2; f0.w = r3;
            float4 f1; f1.x = r4; f1.y = r5; f1.z = r6; f1.w = r7;
            ((float4*)outv)[2 * oq]     = f0;
            ((float4*)outv)[2 * oq + 1] = f1;
        }
    } else if (MODE == 2) {
        uint4 pv;
        pv.x = pkh(s0, s1); pv.y = pkh(s2, s3); pv.z = pkh(s4, s5); pv.w = pkh(s6, s7);
        ((uint4*)xn)[oq] = pv;
        if (isbf) {
            uint4 ov = ((uint4*)outv)[oq];
            float r0 = bflo(ov.x) + 0.25f * s0;
            float r1 = bfhi(ov.x) + 0.25f * s1;
            float r2 = bflo(ov.y) + 0.25f * s2;
            float r3 = bfhi(ov.y) + 0.25f * s3;
            float r4 = bflo(ov.z) + 0.25f * s4;
            float r5 = bfhi(ov.z) + 0.25f * s5;
            float r6 = bflo(ov.w) + 0.25f * s6;
            float r7 = bfhi(ov.w) + 0.25f * s7;
            uint4 nv;
            nv.x = pk(r0, r1); nv.y = pk(r2, r3); nv.z = pk(r4, r5); nv.w = pk(r6, r7);
            ((uint4*)outv)[oq] = nv;
        } else {
            float4 o0 = ((float4*)outv)[2 * oq];
            float4 o1 = ((float4*)outv)[2 * oq + 1];
            o0.x += 0.25f * s0; o0.y += 0.25f * s1; o0.z += 0.25f * s2; o0.w += 0.25f * s3;
            o1.x += 0.25f * s4; o1.y += 0.25f * s5; o1.z += 0.25f * s6; o1.w += 0.25f * s7;
            ((float4*)outv)[2 * oq]     = o0;
            ((float4*)outv)[2 * oq + 1] = o1;
        }
    } else {
        if (isbf) {
            uint4 ov = ((uint4*)outv)[oq];
            float r0 = bflo(ov.x) + 0.25f * s0;
            float r1 = bfhi(ov.x) + 0.25f * s1;
            float r2 = bflo(ov.y) + 0.25f * s2;
            float r3 = bfhi(ov.y) + 0.25f * s3;
            float r4 = bflo(ov.z) + 0.25f * s4;
            float r5 = bfhi(ov.z) + 0.25f * s5;
            float r6 = bflo(ov.w) + 0.25f * s6;
            float r7 = bfhi(ov.w) + 0.25f * s7;
            uint4 nv;
            nv.x = pk(r0, r1); nv.y = pk(r2, r3); nv.z = pk(r4, r5); nv.w = pk(r6, r7);
            ((uint4*)outv)[oq] = nv;
        } else {
            float4 o0 = ((float4*)outv)[2 * oq];
            float4 o1 = ((float4*)outv)[2 * oq + 1];
            o0.x += 0.25f * s0; o0.y += 0.25f * s1; o0.z += 0.25f * s2; o0.w += 0.25f * s3;
            o1.x += 0.25f * s4; o1.y += 0.25f * s5; o1.z += 0.25f * s6; o1.w += 0.25f * s7;
            ((float4*)outv)[2 * oq]     = o0;
            ((float4*)outv)[2 * oq + 1] = o1;
        }
    }
}

// ---------------- host ----------------
static inline size_t align256(size_t x) { return (x + 255) & ~(size_t)255; }

extern "C" void kernel_launch(void* const* d_in, const int* in_sizes, int n_in,
                              void* d_out, int out_size, void* d_ws, size_t ws_size,
                              hipStream_t stream) {
    const int* es = (const int*)d_in[3];
    const int* ed = (const int*)d_in[4];

    char* wsb = (char*)d_ws;
    size_t off = 0;
    int*  flag    = (int*)wsb;               off = align256(off + sizeof(int));
    int*  tot     = (int*)(wsb + off);       off = align256(off + (size_t)NBUCKET * 4);
    int*  bbase   = (int*)(wsb + off);       off = align256(off + (size_t)(NBUCKET + 1) * 4);
    int*  gres    = (int*)(wsb + off);       off = align256(off + (size_t)NBUCKET * 4);
    int*  M       = (int*)(wsb + off);       off = align256(off + (size_t)NB_HIST * NBUCKET * 4);
    int*  row_ptr = (int*)(wsb + off);       off = align256(off + (size_t)(N_NODES + 1) * 4);
    int2* sedge   = (int2*)(wsb + off);      off = align256(off + (size_t)N_EDGES * 8);
    size_t z_off = off;
    // aux (32 MB) aliases x0: bucket_csr consumes aux before init writes x0.
    int2* aux = (int2*)(wsb + z_off);

    const size_t hbuf = (size_t)N_ELEM * 2;   // 32 MB per f16 state buffer

    const int eb = 256;
    const int egrid = (N_ELEM / 4 + eb - 1) / eb;         // init, x4-vectorized
    const int sgrid = (N_NODES + 3) / 4;                  // 62500 blocks, 4 waves each

    // ---- build: totals(+probe fused) -> scan -> LDS-sorted binning -> bucket CSR ----
    hipMemsetAsync(tot, 0, (size_t)NBUCKET * 4, stream);
    hist_bucket<<<NB_HIST, eb, 0, stream>>>(ed, (const unsigned short*)d_in[0], flag, M, tot);
    scan_bbase<<<1, 256, 0, stream>>>(tot, bbase, gres, row_ptr);
    bin_scatter<<<NB_HIST, eb, 0, stream>>>(es, ed, d_in[2], flag, M, gres, aux);
    bucket_csr<<<NBUCKET, BNODES, 0, stream>>>(bbase, aux, row_ptr, sedge);

    size_t need_t1 = z_off + 3 * hbuf;   // ~130 MB

    if (ws_size >= need_t1) {
        // T1: f16 x0,x1,x2; last spmm fuses the 4-term average into d_out
        unsigned int* x0 = (unsigned int*)(wsb + z_off);
        unsigned int* x1 = (unsigned int*)(wsb + z_off + hbuf);
        unsigned int* x2 = (unsigned int*)(wsb + z_off + 2 * hbuf);
        init_kernel<<<egrid, eb, 0, stream>>>(d_in[0], d_in[1], flag, x0, nullptr);
        spmm_csr<0><<<sgrid, eb, 0, stream>>>(row_ptr, sedge, x0, x1, nullptr, nullptr, nullptr, flag);
        spmm_csr<0><<<sgrid, eb, 0, stream>>>(row_ptr, sedge, x1, x2, nullptr, nullptr, nullptr, flag);
        spmm_csr<1><<<sgrid, eb, 0, stream>>>(row_ptr, sedge, x2, nullptr, x0, x1, d_out, flag);
    } else {
        // T2: f16 x, xn; accumulate into d_out (RMW)
        unsigned int* x  = (unsigned int*)(wsb + z_off);
        unsigned int* xn = (unsigned int*)(wsb + z_off + hbuf);
        init_kernel<<<egrid, eb, 0, stream>>>(d_in[0], d_in[1], flag, x, d_out);
        spmm_csr<2><<<sgrid, eb, 0, stream>>>(row_ptr, sedge, x,  xn, nullptr, nullptr, d_out, flag);
        spmm_csr<2><<<sgrid, eb, 0, stream>>>(row_ptr, sedge, xn, x,  nullptr, nullptr, d_out, flag);
        spmm_csr<3><<<sgrid, eb, 0, stream>>>(row_ptr, sedge, x,  nullptr, nullptr, nullptr, d_out, flag);
    }
}